// Round 1
// baseline (3820.120 us; speedup 1.0000x reference)
//
#include <hip/hip_runtime.h>

#define D 128

// ---------------- degree: weighted out/in degree via f32 HW atomics ----------
__global__ __launch_bounds__(256) void degree_kernel(
    const int* __restrict__ src, const int* __restrict__ dst,
    const float* __restrict__ w, float* __restrict__ deg_out,
    float* __restrict__ deg_in, int E)
{
    int e = blockIdx.x * 256 + threadIdx.x;
    if (e >= E) return;
    float we = w[e];
    unsafeAtomicAdd(&deg_out[src[e]], we);
    unsafeAtomicAdd(&deg_in[dst[e]], we);
}

// ---------------- projection: out[m][n] = sum_k h[m][k] * W[k][n] ------------
// TILE_M = 32 rows/block, 256 threads, 4x4 micro-tile, K chunked by 64.
__global__ __launch_bounds__(256) void proj_kernel(
    const float* __restrict__ h, const float* __restrict__ W,
    float* __restrict__ out)
{
    __shared__ float Ws[64 * D];   // 32 KB  (K-chunk x N)
    __shared__ float Hs[32 * D];   // 16 KB  (M-tile x K)
    const int t = threadIdx.x;
    const int row0 = blockIdx.x * 32;

    // stage H tile: 32*128 = 4096 floats = 1024 float4
    const float4* H4 = (const float4*)(h + (size_t)row0 * D);
    float4* Hs4 = (float4*)Hs;
#pragma unroll
    for (int i = 0; i < 4; ++i) Hs4[t + 256 * i] = H4[t + 256 * i];

    const int c0 = (t & 31) * 4;   // 32 col-groups x 4 cols
    const int r0 = (t >> 5) * 4;   // 8 row-groups  x 4 rows
    float acc[4][4] = {};

    for (int kc = 0; kc < 2; ++kc) {
        __syncthreads();           // previous chunk fully consumed
        // stage W chunk: 64*128 = 8192 floats = 2048 float4
        const float4* W4 = (const float4*)(W + (size_t)kc * 64 * D);
        float4* Ws4 = (float4*)Ws;
#pragma unroll
        for (int i = 0; i < 8; ++i) Ws4[t + 256 * i] = W4[t + 256 * i];
        __syncthreads();

        for (int k = 0; k < 64; ++k) {
            float4 wv = *(const float4*)&Ws[k * D + c0];
            float h0 = Hs[(r0 + 0) * D + kc * 64 + k];
            float h1 = Hs[(r0 + 1) * D + kc * 64 + k];
            float h2 = Hs[(r0 + 2) * D + kc * 64 + k];
            float h3 = Hs[(r0 + 3) * D + kc * 64 + k];
            acc[0][0] += h0 * wv.x; acc[0][1] += h0 * wv.y; acc[0][2] += h0 * wv.z; acc[0][3] += h0 * wv.w;
            acc[1][0] += h1 * wv.x; acc[1][1] += h1 * wv.y; acc[1][2] += h1 * wv.z; acc[1][3] += h1 * wv.w;
            acc[2][0] += h2 * wv.x; acc[2][1] += h2 * wv.y; acc[2][2] += h2 * wv.z; acc[2][3] += h2 * wv.w;
            acc[3][0] += h3 * wv.x; acc[3][1] += h3 * wv.y; acc[3][2] += h3 * wv.z; acc[3][3] += h3 * wv.w;
        }
    }

#pragma unroll
    for (int r = 0; r < 4; ++r) {
        float4 v = make_float4(acc[r][0], acc[r][1], acc[r][2], acc[r][3]);
        *(float4*)&out[(size_t)(row0 + r0 + r) * D + c0] = v;
    }
}

// ---------------- scatter: one wave (64 lanes) per edge ----------------------
__global__ __launch_bounds__(256) void scatter_kernel(
    const int* __restrict__ src, const int* __restrict__ dst,
    const float* __restrict__ w, const float* __restrict__ deg_out,
    const float* __restrict__ deg_in, const float* __restrict__ hp,
    float* __restrict__ tmp, int E)
{
    int wid = (blockIdx.x * 256 + threadIdx.x) >> 6;
    int lane = threadIdx.x & 63;
    if (wid >= E) return;
    int s = src[wid];
    int d = dst[wid];
    float wn = w[wid] * rsqrtf(deg_out[s] * deg_in[d]);
    float2 hv = *(const float2*)&hp[(size_t)s * D + lane * 2];
    float* tp = &tmp[(size_t)d * D + lane * 2];
    unsafeAtomicAdd(tp, hv.x * wn);
    unsafeAtomicAdd(tp + 1, hv.y * wn);
}

// ---------------- finalize: out (=|+=) 0.5*relu(tmp+b); re-zero tmp ----------
__global__ __launch_bounds__(256) void finalize_kernel(
    float* __restrict__ tmp, const float* __restrict__ b,
    float* __restrict__ out, int n4, int add)
{
    int i = blockIdx.x * 256 + threadIdx.x;
    if (i >= n4) return;
    float4 v = ((const float4*)tmp)[i];
    int d0 = (i * 4) & (D - 1);
    float4 bv = *(const float4*)&b[d0];
    float4 r;
    r.x = 0.5f * fmaxf(v.x + bv.x, 0.0f);
    r.y = 0.5f * fmaxf(v.y + bv.y, 0.0f);
    r.z = 0.5f * fmaxf(v.z + bv.z, 0.0f);
    r.w = 0.5f * fmaxf(v.w + bv.w, 0.0f);
    if (add) {
        float4 o = ((const float4*)out)[i];
        r.x += o.x; r.y += o.y; r.z += o.z; r.w += o.w;
    }
    ((float4*)out)[i] = r;
    ((float4*)tmp)[i] = make_float4(0.0f, 0.0f, 0.0f, 0.0f);
}

extern "C" void kernel_launch(void* const* d_in, const int* in_sizes, int n_in,
                              void* d_out, int out_size, void* d_ws, size_t ws_size,
                              hipStream_t stream) {
    const float* com_emb = (const float*)d_in[0];
    const float* pos_emb = (const float*)d_in[1];
    const int N = in_sizes[0] / D;   // 40000 (N_COM == N_POS)
    const int E = in_sizes[2];       // 1,000,000

    float* out = (float*)d_out;
    float* out_com = out;
    float* out_pos = out + (size_t)N * D;

    // ws layout: [deg: 4 rel x 2 x N] [tmp: N*D] [hp: N*D]  (~42.2 MB)
    float* ws  = (float*)d_ws;
    float* deg = ws;
    float* tmp = ws + (size_t)8 * N;
    float* hp  = tmp + (size_t)N * D;

    // zero degrees + accumulator (runs in every graph replay)
    hipMemsetAsync(deg, 0, ((size_t)8 * N + (size_t)N * D) * sizeof(float), stream);

    const int degBlocks  = (E + 255) / 256;
    const int projBlocks = N / 32;
    const int scatBlocks = (E + 3) / 4;          // 1 wave per edge, 4 edges/block
    const int n4         = N * D / 4;
    const int finBlocks  = (n4 + 255) / 256;

    auto run_rel = [&](int r, const int* s, const int* d, const float* w,
                       const float* h, const float* W, const float* b,
                       float* oh, int add) {
        float* dout = deg + (size_t)r * 2 * N;
        float* din  = dout + N;
        degree_kernel<<<degBlocks, 256, 0, stream>>>(s, d, w, dout, din, E);
        proj_kernel<<<projBlocks, 256, 0, stream>>>(h, W, hp);
        scatter_kernel<<<scatBlocks, 256, 0, stream>>>(s, d, w, dout, din, hp, tmp, E);
        finalize_kernel<<<finBlocks, 256, 0, stream>>>(tmp, b, oh, n4, add);
    };

    // order matters: store-mode relation must precede add-mode per output half
    // cflow:  com->com  (store com half)
    run_rel(0, (const int*)d_in[8],  (const int*)d_in[9],  (const float*)d_in[10],
            com_emb, (const float*)d_in[18], (const float*)d_in[19], out_com, 0);
    // supply: pos->com  (add com half)
    run_rel(1, (const int*)d_in[5],  (const int*)d_in[6],  (const float*)d_in[7],
            pos_emb, (const float*)d_in[16], (const float*)d_in[17], out_com, 1);
    // pflow:  pos->pos  (store pos half)
    run_rel(2, (const int*)d_in[11], (const int*)d_in[12], (const float*)d_in[13],
            pos_emb, (const float*)d_in[20], (const float*)d_in[21], out_pos, 0);
    // demand: com->pos  (add pos half)
    run_rel(3, (const int*)d_in[2],  (const int*)d_in[3],  (const float*)d_in[4],
            com_emb, (const float*)d_in[14], (const float*)d_in[15], out_pos, 1);
}

// Round 2
// 1478.974 us; speedup vs baseline: 2.5830x; 2.5830x over previous
//
#include <hip/hip_runtime.h>

#define D 128

// ---- pass 1: weighted degrees (f32 HW atomics) + in-degree counts ----------
__global__ __launch_bounds__(256) void degcnt_kernel(
    const int* __restrict__ src, const int* __restrict__ dst,
    const float* __restrict__ w, float* __restrict__ deg_out,
    float* __restrict__ deg_in, int* __restrict__ cnt, int E)
{
    int e = blockIdx.x * 256 + threadIdx.x;
    if (e >= E) return;
    float we = w[e];
    int d = dst[e];
    unsafeAtomicAdd(&deg_out[src[e]], we);
    unsafeAtomicAdd(&deg_in[d], we);
    atomicAdd(&cnt[d], 1);
}

// ---- pass 2: single-block exclusive scan (1024 thr, shfl-based) ------------
__global__ __launch_bounds__(1024) void scan_kernel(
    const int* __restrict__ cnt, int* __restrict__ row_ptr,
    int* __restrict__ cursor, int n)
{
    __shared__ int wsum[16];
    __shared__ int total;
    const int tid = threadIdx.x;
    const int lane = tid & 63;
    const int wid = tid >> 6;
    if (tid == 0) total = 0;
    __syncthreads();
    for (int base = 0; base < n; base += 1024) {
        int i = base + tid;
        int v = (i < n) ? cnt[i] : 0;
        int x = v;
#pragma unroll
        for (int off = 1; off < 64; off <<= 1) {
            int y = __shfl_up(x, off, 64);
            if (lane >= off) x += y;
        }
        if (lane == 63) wsum[wid] = x;
        __syncthreads();
        if (wid == 0) {
            int y = (lane < 16) ? wsum[lane] : 0;
#pragma unroll
            for (int off = 1; off < 16; off <<= 1) {
                int t = __shfl_up(y, off, 64);
                if (lane >= off) y += t;
            }
            if (lane < 16) wsum[lane] = y;
        }
        __syncthreads();
        int waveoff = (wid > 0) ? wsum[wid - 1] : 0;
        int excl = total + waveoff + x - v;
        if (i < n) { row_ptr[i] = excl; cursor[i] = excl; }
        __syncthreads();                 // all reads of `total` complete
        if (tid == 0) total += wsum[15];
        __syncthreads();
    }
    if (threadIdx.x == 0) row_ptr[n] = total;
}

// ---- pass 3: bucket edges by dst; precompute normalized weight -------------
__global__ __launch_bounds__(256) void fill_kernel(
    const int* __restrict__ src, const int* __restrict__ dst,
    const float* __restrict__ w, const float* __restrict__ deg_out,
    const float* __restrict__ deg_in, int* __restrict__ cursor,
    int* __restrict__ csr_src, float* __restrict__ csr_wn, int E)
{
    int e = blockIdx.x * 256 + threadIdx.x;
    if (e >= E) return;
    int s = src[e];
    int d = dst[e];
    int pos = atomicAdd(&cursor[d], 1);
    csr_src[pos] = s;
    csr_wn[pos] = w[e] * rsqrtf(deg_out[s] * deg_in[d]);
}

// ---- pass 4: pull-aggregate raw features; one wave per dst node ------------
__global__ __launch_bounds__(256) void gather_kernel(
    const int* __restrict__ row_ptr, const int* __restrict__ csr_src,
    const float* __restrict__ csr_wn, const float* __restrict__ h,
    float* __restrict__ agg, int n)
{
    int node = (blockIdx.x * 256 + threadIdx.x) >> 6;
    int lane = threadIdx.x & 63;
    if (node >= n) return;
    int beg = row_ptr[node], end = row_ptr[node + 1];
    float2 acc = make_float2(0.0f, 0.0f);
    for (int e = beg; e < end; ++e) {
        int s = csr_src[e];
        float wn = csr_wn[e];
        float2 hv = *(const float2*)(h + (size_t)s * D + lane * 2);
        acc.x += wn * hv.x;
        acc.y += wn * hv.y;
    }
    *(float2*)(agg + (size_t)node * D + lane * 2) = acc;
}

// ---- pass 5: project aggregate, fused bias+ReLU+0.5*merge ------------------
// 32 rows/block, 256 threads, 4x4 micro-tile, K chunked by 64.
__global__ __launch_bounds__(256) void proj_fused_kernel(
    const float* __restrict__ h, const float* __restrict__ W,
    const float* __restrict__ b, float* __restrict__ out, int add)
{
    __shared__ float Ws[64 * D];   // 32 KB
    __shared__ float Hs[32 * D];   // 16 KB
    const int t = threadIdx.x;
    const int row0 = blockIdx.x * 32;

    const float4* H4 = (const float4*)(h + (size_t)row0 * D);
    float4* Hs4 = (float4*)Hs;
#pragma unroll
    for (int i = 0; i < 4; ++i) Hs4[t + 256 * i] = H4[t + 256 * i];

    const int c0 = (t & 31) * 4;
    const int r0 = (t >> 5) * 4;
    float acc[4][4] = {};

    for (int kc = 0; kc < 2; ++kc) {
        __syncthreads();
        const float4* W4 = (const float4*)(W + (size_t)kc * 64 * D);
        float4* Ws4 = (float4*)Ws;
#pragma unroll
        for (int i = 0; i < 8; ++i) Ws4[t + 256 * i] = W4[t + 256 * i];
        __syncthreads();

        for (int k = 0; k < 64; ++k) {
            float4 wv = *(const float4*)&Ws[k * D + c0];
            float h0 = Hs[(r0 + 0) * D + kc * 64 + k];
            float h1 = Hs[(r0 + 1) * D + kc * 64 + k];
            float h2 = Hs[(r0 + 2) * D + kc * 64 + k];
            float h3 = Hs[(r0 + 3) * D + kc * 64 + k];
            acc[0][0] += h0 * wv.x; acc[0][1] += h0 * wv.y; acc[0][2] += h0 * wv.z; acc[0][3] += h0 * wv.w;
            acc[1][0] += h1 * wv.x; acc[1][1] += h1 * wv.y; acc[1][2] += h1 * wv.z; acc[1][3] += h1 * wv.w;
            acc[2][0] += h2 * wv.x; acc[2][1] += h2 * wv.y; acc[2][2] += h2 * wv.z; acc[2][3] += h2 * wv.w;
            acc[3][0] += h3 * wv.x; acc[3][1] += h3 * wv.y; acc[3][2] += h3 * wv.z; acc[3][3] += h3 * wv.w;
        }
    }

    float4 bv = *(const float4*)&b[c0];
#pragma unroll
    for (int r = 0; r < 4; ++r) {
        float* op = &out[(size_t)(row0 + r0 + r) * D + c0];
        float4 v;
        v.x = 0.5f * fmaxf(acc[r][0] + bv.x, 0.0f);
        v.y = 0.5f * fmaxf(acc[r][1] + bv.y, 0.0f);
        v.z = 0.5f * fmaxf(acc[r][2] + bv.z, 0.0f);
        v.w = 0.5f * fmaxf(acc[r][3] + bv.w, 0.0f);
        if (add) {
            float4 o = *(const float4*)op;
            v.x += o.x; v.y += o.y; v.z += o.z; v.w += o.w;
        }
        *(float4*)op = v;
    }
}

extern "C" void kernel_launch(void* const* d_in, const int* in_sizes, int n_in,
                              void* d_out, int out_size, void* d_ws, size_t ws_size,
                              hipStream_t stream) {
    const float* com_emb = (const float*)d_in[0];
    const float* pos_emb = (const float*)d_in[1];
    const int N = in_sizes[0] / D;   // 40000
    const int E = in_sizes[2];       // 1,000,000

    float* out = (float*)d_out;
    float* out_com = out;
    float* out_pos = out + (size_t)N * D;

    // ws layout (floats/ints, all 4B):
    // [deg: 4 rel x 2N f] [cnt: 4 rel x N i] [row_ptr: N+1 i] [cursor: N i]
    // [csr_src: E i] [csr_wn: E f] [agg: N*D f]   ~= 30.7 MB
    char* p = (char*)d_ws;
    float* deg    = (float*)p;               p += (size_t)8 * N * 4;
    int*   cnt    = (int*)p;                 p += (size_t)4 * N * 4;
    int*   row_ptr= (int*)p;                 p += (size_t)(N + 1) * 4;
    int*   cursor = (int*)p;                 p += (size_t)N * 4;
    int*   csr_src= (int*)p;                 p += (size_t)E * 4;
    float* csr_wn = (float*)p;               p += (size_t)E * 4;
    float* agg    = (float*)p;

    // zero all degrees + counts once per call (12N * 4B = 1.92 MB)
    hipMemsetAsync(deg, 0, (size_t)12 * N * 4, stream);

    const int eBlocks   = (E + 255) / 256;
    const int gBlocks   = (N + 3) / 4;       // 1 wave per dst node
    const int pBlocks   = N / 32;

    auto run_rel = [&](int r, const int* s, const int* d, const float* w,
                       const float* h, const float* W, const float* b,
                       float* oh, int add) {
        float* dout = deg + (size_t)r * 2 * N;
        float* din  = dout + N;
        int*   cn   = cnt + (size_t)r * N;
        degcnt_kernel<<<eBlocks, 256, 0, stream>>>(s, d, w, dout, din, cn, E);
        scan_kernel<<<1, 1024, 0, stream>>>(cn, row_ptr, cursor, N);
        fill_kernel<<<eBlocks, 256, 0, stream>>>(s, d, w, dout, din, cursor,
                                                 csr_src, csr_wn, E);
        gather_kernel<<<gBlocks, 256, 0, stream>>>(row_ptr, csr_src, csr_wn,
                                                   h, agg, N);
        proj_fused_kernel<<<pBlocks, 256, 0, stream>>>(agg, W, b, oh, add);
    };

    // store-mode relation first per output half, then add-mode
    // cflow:  com->com  (store com half)
    run_rel(0, (const int*)d_in[8],  (const int*)d_in[9],  (const float*)d_in[10],
            com_emb, (const float*)d_in[18], (const float*)d_in[19], out_com, 0);
    // supply: pos->com  (add com half)
    run_rel(1, (const int*)d_in[5],  (const int*)d_in[6],  (const float*)d_in[7],
            pos_emb, (const float*)d_in[16], (const float*)d_in[17], out_com, 1);
    // pflow:  pos->pos  (store pos half)
    run_rel(2, (const int*)d_in[11], (const int*)d_in[12], (const float*)d_in[13],
            pos_emb, (const float*)d_in[20], (const float*)d_in[21], out_pos, 0);
    // demand: com->pos  (add pos half)
    run_rel(3, (const int*)d_in[2],  (const int*)d_in[3],  (const float*)d_in[4],
            com_emb, (const float*)d_in[14], (const float*)d_in[15], out_pos, 1);
}

// Round 3
// 1144.499 us; speedup vs baseline: 3.3378x; 1.2922x over previous
//
#include <hip/hip_runtime.h>

#define D  128
#define NN 40000
#define RR 4          // histogram/cursor replication factor

struct Ptrs { const int* src[4]; const int* dst[4]; const float* w[4]; };

// ---- phase A: fused over 4 relations: dst-counts + weighted out-degree -----
// replicated R=4 by edge-block to cut per-line atomic contention 4x
__global__ __launch_bounds__(256) void degcnt4_kernel(
    Ptrs p, int* __restrict__ cnt_rep, float* __restrict__ dego_rep,
    int eBlocks, int E)
{
    int rel = blockIdx.x / eBlocks;
    int b   = blockIdx.x - rel * eBlocks;
    int rep = b & (RR - 1);
    int e   = b * 256 + threadIdx.x;
    if (e >= E) return;
    int s = p.src[rel][e];
    int d = p.dst[rel][e];
    float we = p.w[rel][e];
    atomicAdd(&cnt_rep[((rel * RR + rep) * NN) + d], 1);
    unsafeAtomicAdd(&dego_rep[((rel * RR + rep) * NN) + s], we);
}

// ---- phase B: reduce out-degree replicas -----------------------------------
__global__ __launch_bounds__(256) void reduce_dego_kernel(
    const float* __restrict__ dego_rep, float* __restrict__ dego, int n4)
{
    int i = blockIdx.x * 256 + threadIdx.x;   // i = rel*NN + s
    if (i >= n4) return;
    int rel = i / NN;
    int s   = i - rel * NN;
    float v = 0.f;
#pragma unroll
    for (int r = 0; r < RR; ++r) v += dego_rep[(rel * RR + r) * NN + s];
    dego[i] = v;
}

// ---- block-wide exclusive scan helper (1024 threads, 16 waves) -------------
__device__ inline int block_excl_scan(int v, int tid) {
    __shared__ int wsum[16];
    int lane = tid & 63, wid = tid >> 6;
    int x = v;
#pragma unroll
    for (int off = 1; off < 64; off <<= 1) {
        int y = __shfl_up(x, off, 64);
        if (lane >= off) x += y;
    }
    if (lane == 63) wsum[wid] = x;
    __syncthreads();
    if (wid == 0) {
        int y = (lane < 16) ? wsum[lane] : 0;
#pragma unroll
        for (int off = 1; off < 16; off <<= 1) {
            int t = __shfl_up(y, off, 64);
            if (lane >= off) y += t;
        }
        if (lane < 16) wsum[lane] = y;
    }
    __syncthreads();
    int woff = wid ? wsum[wid - 1] : 0;
    return woff + x - v;               // exclusive prefix within block
}

// ---- phase C: 3-kernel scan over [rel][d][rep] counts (4*NN*RR elems) ------
__global__ __launch_bounds__(1024) void scan1_kernel(
    const int* __restrict__ cnt_rep, int* __restrict__ scanex,
    int* __restrict__ bsum, int total)
{
    int tid = threadIdx.x;
    int i = blockIdx.x * 1024 + tid;
    int v = 0;
    if (i < total) {
        int rel = i / (NN * RR);
        int rem = i - rel * (NN * RR);
        int d = rem >> 2, rep = rem & (RR - 1);
        v = cnt_rep[(rel * RR + rep) * NN + d];
    }
    int excl = block_excl_scan(v, tid);
    if (i < total) scanex[i] = excl;
    if (tid == 1023) bsum[blockIdx.x] = excl + v;
}

__global__ __launch_bounds__(1024) void scan2_kernel(int* __restrict__ bsum, int nb)
{
    int tid = threadIdx.x;
    int v = (tid < nb) ? bsum[tid] : 0;
    int excl = block_excl_scan(v, tid);
    if (tid < nb) bsum[tid] = excl;
}

__global__ __launch_bounds__(256) void scan3_kernel(
    const int* __restrict__ scanex, const int* __restrict__ bsum,
    int* __restrict__ cursor4, int* __restrict__ row_ptr, int total, int E)
{
    int i = blockIdx.x * 256 + threadIdx.x;
    if (i >= total) return;
    int v = scanex[i] + bsum[i >> 10];
    int rel = i / (NN * RR);
    int rem = i - rel * (NN * RR);
    int d = rem >> 2, rep = rem & (RR - 1);
    int local = v - rel * E;           // each relation has exactly E edges
    cursor4[(rel * NN + d) * RR + rep] = local;
    if (rep == 0) row_ptr[rel * (NN + 1) + d] = local;
    if (i < 4) row_ptr[i * (NN + 1) + NN] = E;
}

// ---- phase D: bucket edges by dst (stable per replica); raw w kept ---------
__global__ __launch_bounds__(256) void fill_kernel(
    const int* __restrict__ src, const int* __restrict__ dst,
    const float* __restrict__ w, int* __restrict__ cursor4_r,
    unsigned long long* __restrict__ csr8, int E)
{
    int rep = blockIdx.x & (RR - 1);
    int e = blockIdx.x * 256 + threadIdx.x;
    if (e >= E) return;
    int s = src[e];
    int d = dst[e];
    int pos = atomicAdd(&cursor4_r[d * RR + rep], 1);
    unsigned long long rec =
        (unsigned long long)(unsigned)s |
        ((unsigned long long)__float_as_uint(w[e]) << 32);
    csr8[pos] = rec;
}

// ---- phase E: pull-aggregate; one wave per dst node; deg_in inline ---------
__global__ __launch_bounds__(256) void gather_kernel(
    const int* __restrict__ row_ptr_r, const unsigned long long* __restrict__ csr8,
    const float* __restrict__ dego_r, const float* __restrict__ h,
    float* __restrict__ agg, int n)
{
    int node = (blockIdx.x * 256 + threadIdx.x) >> 6;
    int lane = threadIdx.x & 63;
    if (node >= n) return;
    int beg = row_ptr_r[node], end = row_ptr_r[node + 1];
    // pass 1: deg_in = sum of raw w over the row (wave-parallel + butterfly)
    float sw = 0.f;
    for (int e = beg + lane; e < end; e += 64)
        sw += __uint_as_float((unsigned)(csr8[e] >> 32));
#pragma unroll
    for (int off = 32; off; off >>= 1) sw += __shfl_xor(sw, off, 64);
    // pass 2: weighted feature accumulation
    float2 acc = make_float2(0.f, 0.f);
    for (int e = beg; e < end; ++e) {
        unsigned long long rec = csr8[e];          // same addr all lanes: broadcast
        int s = (int)(unsigned)rec;
        float we = __uint_as_float((unsigned)(rec >> 32));
        float wn = we * rsqrtf(dego_r[s] * sw);
        float2 hv = *(const float2*)(h + (size_t)s * D + lane * 2);
        acc.x += wn * hv.x;
        acc.y += wn * hv.y;
    }
    *(float2*)(agg + (size_t)node * D + lane * 2) = acc;
}

// ---- phase F: project aggregate, fused bias+ReLU+0.5*merge -----------------
__global__ __launch_bounds__(256) void proj_fused_kernel(
    const float* __restrict__ h, const float* __restrict__ W,
    const float* __restrict__ b, float* __restrict__ out, int add)
{
    __shared__ float Ws[64 * D];
    __shared__ float Hs[32 * D];
    const int t = threadIdx.x;
    const int row0 = blockIdx.x * 32;

    const float4* H4 = (const float4*)(h + (size_t)row0 * D);
    float4* Hs4 = (float4*)Hs;
#pragma unroll
    for (int i = 0; i < 4; ++i) Hs4[t + 256 * i] = H4[t + 256 * i];

    const int c0 = (t & 31) * 4;
    const int r0 = (t >> 5) * 4;
    float acc[4][4] = {};

    for (int kc = 0; kc < 2; ++kc) {
        __syncthreads();
        const float4* W4 = (const float4*)(W + (size_t)kc * 64 * D);
        float4* Ws4 = (float4*)Ws;
#pragma unroll
        for (int i = 0; i < 8; ++i) Ws4[t + 256 * i] = W4[t + 256 * i];
        __syncthreads();

        for (int k = 0; k < 64; ++k) {
            float4 wv = *(const float4*)&Ws[k * D + c0];
            float h0 = Hs[(r0 + 0) * D + kc * 64 + k];
            float h1 = Hs[(r0 + 1) * D + kc * 64 + k];
            float h2 = Hs[(r0 + 2) * D + kc * 64 + k];
            float h3 = Hs[(r0 + 3) * D + kc * 64 + k];
            acc[0][0] += h0 * wv.x; acc[0][1] += h0 * wv.y; acc[0][2] += h0 * wv.z; acc[0][3] += h0 * wv.w;
            acc[1][0] += h1 * wv.x; acc[1][1] += h1 * wv.y; acc[1][2] += h1 * wv.z; acc[1][3] += h1 * wv.w;
            acc[2][0] += h2 * wv.x; acc[2][1] += h2 * wv.y; acc[2][2] += h2 * wv.z; acc[2][3] += h2 * wv.w;
            acc[3][0] += h3 * wv.x; acc[3][1] += h3 * wv.y; acc[3][2] += h3 * wv.z; acc[3][3] += h3 * wv.w;
        }
    }

    float4 bv = *(const float4*)&b[c0];
#pragma unroll
    for (int r = 0; r < 4; ++r) {
        float* op = &out[(size_t)(row0 + r0 + r) * D + c0];
        float4 v;
        v.x = 0.5f * fmaxf(acc[r][0] + bv.x, 0.0f);
        v.y = 0.5f * fmaxf(acc[r][1] + bv.y, 0.0f);
        v.z = 0.5f * fmaxf(acc[r][2] + bv.z, 0.0f);
        v.w = 0.5f * fmaxf(acc[r][3] + bv.w, 0.0f);
        if (add) {
            float4 o = *(const float4*)op;
            v.x += o.x; v.y += o.y; v.z += o.z; v.w += o.w;
        }
        *(float4*)op = v;
    }
}

extern "C" void kernel_launch(void* const* d_in, const int* in_sizes, int n_in,
                              void* d_out, int out_size, void* d_ws, size_t ws_size,
                              hipStream_t stream) {
    const float* com_emb = (const float*)d_in[0];
    const float* pos_emb = (const float*)d_in[1];
    const int E = in_sizes[2];       // 1,000,000
    const int N = NN;

    float* out = (float*)d_out;
    float* out_com = out;
    float* out_pos = out + (size_t)N * D;

    // relation order: 0=cflow(com->com) 1=supply(pos->com) 2=pflow(pos->pos) 3=demand(com->pos)
    Ptrs ptrs;
    ptrs.src[0] = (const int*)d_in[8];  ptrs.dst[0] = (const int*)d_in[9];  ptrs.w[0] = (const float*)d_in[10];
    ptrs.src[1] = (const int*)d_in[5];  ptrs.dst[1] = (const int*)d_in[6];  ptrs.w[1] = (const float*)d_in[7];
    ptrs.src[2] = (const int*)d_in[11]; ptrs.dst[2] = (const int*)d_in[12]; ptrs.w[2] = (const float*)d_in[13];
    ptrs.src[3] = (const int*)d_in[2];  ptrs.dst[3] = (const int*)d_in[3];  ptrs.w[3] = (const float*)d_in[4];

    // ws layout (≈40.0 MB)
    char* p = (char*)d_ws;
    int*   cnt_rep  = (int*)p;                 p += (size_t)4 * RR * N * 4;   // 2.56 MB
    float* dego_rep = (float*)p;               p += (size_t)4 * RR * N * 4;   // 2.56 MB
    float* dego     = (float*)p;               p += (size_t)4 * N * 4;        // 0.64 MB
    int*   scanex   = (int*)p;                 p += (size_t)4 * N * RR * 4;   // 2.56 MB
    int*   bsum     = (int*)p;                 p += (size_t)1024 * 4;         // 4 KB
    int*   cursor4  = (int*)p;                 p += (size_t)4 * N * RR * 4;   // 2.56 MB
    int*   row_ptr  = (int*)p;                 p += (size_t)4 * (N + 1) * 4;  // 0.64 MB
    unsigned long long* csr8 = (unsigned long long*)p; p += (size_t)E * 8;    // 8 MB
    float* agg      = (float*)p;                                              // 20.48 MB

    const int eBlocks = (E + 255) / 256;
    const int total   = 4 * N * RR;            // 640000
    const int sBlocks = total / 1024;          // 625 (exact)

    // zero replicated histograms (cnt_rep + dego_rep are adjacent)
    hipMemsetAsync(cnt_rep, 0, (size_t)8 * RR * N * 4, stream);

    degcnt4_kernel<<<4 * eBlocks, 256, 0, stream>>>(ptrs, cnt_rep, dego_rep, eBlocks, E);
    reduce_dego_kernel<<<(4 * N + 255) / 256, 256, 0, stream>>>(dego_rep, dego, 4 * N);
    scan1_kernel<<<sBlocks, 1024, 0, stream>>>(cnt_rep, scanex, bsum, total);
    scan2_kernel<<<1, 1024, 0, stream>>>(bsum, sBlocks);
    scan3_kernel<<<(total + 255) / 256, 256, 0, stream>>>(scanex, bsum, cursor4, row_ptr, total, E);

    const int gBlocks = N / 4;                 // 1 wave per dst node
    const int pBlocks = N / 32;

    auto run_rel = [&](int rel, const float* h, const float* W, const float* b,
                       float* oh, int add) {
        fill_kernel<<<eBlocks, 256, 0, stream>>>(ptrs.src[rel], ptrs.dst[rel], ptrs.w[rel],
                                                 cursor4 + (size_t)rel * N * RR, csr8, E);
        gather_kernel<<<gBlocks, 256, 0, stream>>>(row_ptr + (size_t)rel * (N + 1), csr8,
                                                   dego + (size_t)rel * N, h, agg, N);
        proj_fused_kernel<<<pBlocks, 256, 0, stream>>>(agg, W, b, oh, add);
    };

    run_rel(0, com_emb, (const float*)d_in[18], (const float*)d_in[19], out_com, 0); // cflow
    run_rel(1, pos_emb, (const float*)d_in[16], (const float*)d_in[17], out_com, 1); // supply
    run_rel(2, pos_emb, (const float*)d_in[20], (const float*)d_in[21], out_pos, 0); // pflow
    run_rel(3, com_emb, (const float*)d_in[14], (const float*)d_in[15], out_pos, 1); // demand
}